// Round 1
// baseline (4824.769 us; speedup 1.0000x reference)
//
#include <hip/hip_runtime.h>
#include <cstdint>
#include <cmath>

// Mamba forward, fp32 baseline.
// Dims (fixed for this problem):
#define V_  50257
#define H_  768
#define D_  1536
#define N_  16
#define K_  4
#define R_  48
#define L_  2
#define B_  2
#define T_  1024
#define BT_ (B_*T_)
#define P2_ (R_ + 2*N_)   // 80
#define EPS_ 1e-5f

// ---------------------------------------------------------------------------
// Embedding gather: h[row, :] = embed[seq[row], :]
__global__ __launch_bounds__(256) void embed_gather_k(const int* __restrict__ seq,
                                                      const float* __restrict__ embed,
                                                      float* __restrict__ h) {
    int row = blockIdx.x;
    int v = seq[row];
    const float4* src = (const float4*)(embed + (size_t)v * H_);
    float4* dst = (float4*)(h + (size_t)row * H_);
    for (int c = threadIdx.x; c < H_ / 4; c += blockDim.x) dst[c] = src[c];
}

// ---------------------------------------------------------------------------
// RMSNorm: out[row,:] = in[row,:] * rsqrt(mean(in^2)+eps) * w[:]
__global__ __launch_bounds__(256) void rmsnorm_k(const float* __restrict__ in,
                                                 const float* __restrict__ w,
                                                 float* __restrict__ out) {
    int row = blockIdx.x;
    const float* p = in + (size_t)row * H_;
    float vals[3];
    float ss = 0.f;
#pragma unroll
    for (int i = 0; i < 3; ++i) {
        float v = p[threadIdx.x + i * 256];
        vals[i] = v;
        ss += v * v;
    }
    // wave64 reduce
#pragma unroll
    for (int m = 32; m >= 1; m >>= 1) ss += __shfl_xor(ss, m);
    __shared__ float wss[4];
    if ((threadIdx.x & 63) == 0) wss[threadIdx.x >> 6] = ss;
    __syncthreads();
    float tot = wss[0] + wss[1] + wss[2] + wss[3];
    float scale = rsqrtf(tot * (1.f / H_) + EPS_);
#pragma unroll
    for (int i = 0; i < 3; ++i) {
        int c = threadIdx.x + i * 256;
        out[(size_t)row * H_ + c] = vals[i] * scale * w[c];
    }
}

// ---------------------------------------------------------------------------
// Generic fp32 GEMM:  C[M,N] (+)= X[M,K] @ W[N,K]^T   (both row-major, dot over K)
// 64x64 tile, BK=16, 256 threads, 4x4 per thread. K must be a multiple of 16.
template <int ADD>
__global__ __launch_bounds__(256) void gemm64_k(const float* __restrict__ X,
                                                const float* __restrict__ W,
                                                float* __restrict__ C,
                                                int M, int N, int K) {
    __shared__ __align__(16) float Xs[16][68];
    __shared__ __align__(16) float Ws[16][68];
    const int bm = blockIdx.y * 64;
    const int bn = blockIdx.x * 64;
    const int tid = threadIdx.x;
    const int tx = tid & 15;    // col quad
    const int ty = tid >> 4;    // row quad
    const int lr = tid >> 2;    // load row 0..63
    const int lk = (tid & 3) * 4;

    float acc[4][4];
#pragma unroll
    for (int i = 0; i < 4; ++i)
#pragma unroll
        for (int j = 0; j < 4; ++j) acc[i][j] = 0.f;

    for (int k0 = 0; k0 < K; k0 += 16) {
        float4 xv = make_float4(0.f, 0.f, 0.f, 0.f);
        float4 wv = make_float4(0.f, 0.f, 0.f, 0.f);
        int xr = bm + lr;
        if (xr < M) xv = *(const float4*)(X + (size_t)xr * K + k0 + lk);
        int wr = bn + lr;
        if (wr < N) wv = *(const float4*)(W + (size_t)wr * K + k0 + lk);
        Xs[lk + 0][lr] = xv.x; Xs[lk + 1][lr] = xv.y; Xs[lk + 2][lr] = xv.z; Xs[lk + 3][lr] = xv.w;
        Ws[lk + 0][lr] = wv.x; Ws[lk + 1][lr] = wv.y; Ws[lk + 2][lr] = wv.z; Ws[lk + 3][lr] = wv.w;
        __syncthreads();
#pragma unroll
        for (int kk = 0; kk < 16; ++kk) {
            float4 av = *(const float4*)&Xs[kk][ty * 4];
            float4 bv = *(const float4*)&Ws[kk][tx * 4];
            float a[4] = {av.x, av.y, av.z, av.w};
            float b[4] = {bv.x, bv.y, bv.z, bv.w};
#pragma unroll
            for (int i = 0; i < 4; ++i)
#pragma unroll
                for (int j = 0; j < 4; ++j) acc[i][j] = fmaf(a[i], b[j], acc[i][j]);
        }
        __syncthreads();
    }
#pragma unroll
    for (int i = 0; i < 4; ++i) {
        int row = bm + ty * 4 + i;
        if (row >= M) continue;
        int col = bn + tx * 4;
        size_t idx = (size_t)row * N + col;
        if (col + 3 < N) {
            float4* cp = (float4*)(C + idx);
            float4 v = make_float4(acc[i][0], acc[i][1], acc[i][2], acc[i][3]);
            if (ADD) {
                float4 o = *cp;
                v.x += o.x; v.y += o.y; v.z += o.z; v.w += o.w;
            }
            *cp = v;
        } else {
#pragma unroll
            for (int j = 0; j < 4; ++j) {
                if (col + j < N) {
                    if (ADD) C[idx + j] += acc[i][j];
                    else C[idx + j] = acc[i][j];
                }
            }
        }
    }
}

// ---------------------------------------------------------------------------
// 128x128 tile fp32 GEMM for the big logits matmul. BK=8, 8x8 per thread.
template <int ADD>
__global__ __launch_bounds__(256) void gemm128_k(const float* __restrict__ X,
                                                 const float* __restrict__ W,
                                                 float* __restrict__ C,
                                                 int M, int N, int K) {
    __shared__ __align__(16) float Xs[8][132];
    __shared__ __align__(16) float Ws[8][132];
    const int bm = blockIdx.y * 128;
    const int bn = blockIdx.x * 128;
    const int tid = threadIdx.x;
    const int tx = tid & 15;    // col octet
    const int ty = tid >> 4;    // row octet
    const int lr = tid >> 1;    // load row 0..127
    const int lk = (tid & 1) * 4;

    float acc[8][8];
#pragma unroll
    for (int i = 0; i < 8; ++i)
#pragma unroll
        for (int j = 0; j < 8; ++j) acc[i][j] = 0.f;

    for (int k0 = 0; k0 < K; k0 += 8) {
        float4 xv = make_float4(0.f, 0.f, 0.f, 0.f);
        float4 wv = make_float4(0.f, 0.f, 0.f, 0.f);
        int xr = bm + lr;
        if (xr < M) xv = *(const float4*)(X + (size_t)xr * K + k0 + lk);
        int wr = bn + lr;
        if (wr < N) wv = *(const float4*)(W + (size_t)wr * K + k0 + lk);
        Xs[lk + 0][lr] = xv.x; Xs[lk + 1][lr] = xv.y; Xs[lk + 2][lr] = xv.z; Xs[lk + 3][lr] = xv.w;
        Ws[lk + 0][lr] = wv.x; Ws[lk + 1][lr] = wv.y; Ws[lk + 2][lr] = wv.z; Ws[lk + 3][lr] = wv.w;
        __syncthreads();
#pragma unroll
        for (int kk = 0; kk < 8; ++kk) {
            float4 a0 = *(const float4*)&Xs[kk][ty * 8];
            float4 a1 = *(const float4*)&Xs[kk][ty * 8 + 4];
            float4 b0 = *(const float4*)&Ws[kk][tx * 8];
            float4 b1 = *(const float4*)&Ws[kk][tx * 8 + 4];
            float a[8] = {a0.x, a0.y, a0.z, a0.w, a1.x, a1.y, a1.z, a1.w};
            float b[8] = {b0.x, b0.y, b0.z, b0.w, b1.x, b1.y, b1.z, b1.w};
#pragma unroll
            for (int i = 0; i < 8; ++i)
#pragma unroll
                for (int j = 0; j < 8; ++j) acc[i][j] = fmaf(a[i], b[j], acc[i][j]);
        }
        __syncthreads();
    }
#pragma unroll
    for (int i = 0; i < 8; ++i) {
        int row = bm + ty * 8 + i;
        if (row >= M) continue;
#pragma unroll
        for (int j4 = 0; j4 < 8; j4 += 4) {
            int col = bn + tx * 8 + j4;
            size_t idx = (size_t)row * N + col;
            if (col + 3 < N) {
                float4* cp = (float4*)(C + idx);
                float4 v = make_float4(acc[i][j4], acc[i][j4 + 1], acc[i][j4 + 2], acc[i][j4 + 3]);
                if (ADD) {
                    float4 o = *cp;
                    v.x += o.x; v.y += o.y; v.z += o.z; v.w += o.w;
                }
                *cp = v;
            } else {
#pragma unroll
                for (int j = 0; j < 4; ++j) {
                    if (col + j < N) {
                        if (ADD) C[idx + j] += acc[i][j4 + j];
                        else C[idx + j] = acc[i][j4 + j];
                    }
                }
            }
        }
    }
}

// ---------------------------------------------------------------------------
// Causal depthwise conv (K=4) + SiLU.  xs = proj[:, :D], xc = silu(conv(xs))
__global__ __launch_bounds__(256) void conv_silu_k(const float* __restrict__ proj,
                                                   const float* __restrict__ cw,
                                                   const float* __restrict__ cb,
                                                   float* __restrict__ xc) {
    int idx = blockIdx.x * 256 + threadIdx.x;   // over BT*D
    int d = idx % D_;
    int row = idx / D_;
    int t = row & (T_ - 1);
    float acc = cb[d];
    const float* base = proj + (size_t)row * (2 * D_) + d;
#pragma unroll
    for (int k = 0; k < K_; ++k) {
        int tt = t - (K_ - 1) + k;
        if (tt >= 0) acc = fmaf(base[(ptrdiff_t)(k - (K_ - 1)) * (2 * D_)], cw[d * K_ + k], acc);
    }
    xc[idx] = acc / (1.f + expf(-acc));  // silu
}

// ---------------------------------------------------------------------------
// dt = softplus(dt_in @ dpw^T + dpb), dt_in = p2[:, :R]
__global__ __launch_bounds__(256) void dt_k(const float* __restrict__ p2,
                                            const float* __restrict__ dpw,
                                            const float* __restrict__ dpb,
                                            float* __restrict__ dt) {
    int row = blockIdx.y;
    int d = blockIdx.x * 256 + threadIdx.x;
    __shared__ float din[R_];
    if (threadIdx.x < R_) din[threadIdx.x] = p2[(size_t)row * P2_ + threadIdx.x];
    __syncthreads();
    float acc = dpb[d];
    const float* wrow = dpw + (size_t)d * R_;
#pragma unroll
    for (int r = 0; r < R_; ++r) acc = fmaf(din[r], wrow[r], acc);
    float sp = (acc > 20.f) ? acc : log1pf(expf(acc));
    dt[(size_t)row * D_ + d] = sp;
}

// ---------------------------------------------------------------------------
// Selective scan along T, fused with C-contraction, D-skip, and gate*silu.
// One thread per (d-local, n); block = 16 d x 16 n; grid = (D/16, B).
__global__ __launch_bounds__(256) void scan_k(const float* __restrict__ dt,
                                              const float* __restrict__ xc,
                                              const float* __restrict__ p2,
                                              const float* __restrict__ al,
                                              const float* __restrict__ Dp,
                                              const float* __restrict__ proj,
                                              float* __restrict__ y) {
    int b = blockIdx.y;
    int n = threadIdx.x & 15;
    int dl = threadIdx.x >> 4;
    int d = blockIdx.x * 16 + dl;
    float A = -expf(al[(size_t)d * N_ + n]);
    float dd = Dp[d];
    float h = 0.f;
    const size_t rowbase = (size_t)b * T_;
    for (int t = 0; t < T_; ++t) {
        size_t row = rowbase + t;
        float dtv = dt[row * D_ + d];
        float xcv = xc[row * D_ + d];
        float Bv = p2[row * P2_ + R_ + n];
        float Cv = p2[row * P2_ + R_ + N_ + n];
        float dA = expf(dtv * A);
        h = fmaf(dA, h, (dtv * xcv) * Bv);
        float contrib = h * Cv;
        contrib += __shfl_xor(contrib, 1);
        contrib += __shfl_xor(contrib, 2);
        contrib += __shfl_xor(contrib, 4);
        contrib += __shfl_xor(contrib, 8);
        if (n == 0) {
            float yv = contrib + xcv * dd;
            float g = proj[row * (2 * D_) + D_ + d];
            yv *= g / (1.f + expf(-g));
            y[row * D_ + d] = yv;
        }
    }
}

// ---------------------------------------------------------------------------
extern "C" void kernel_launch(void* const* d_in, const int* in_sizes, int n_in,
                              void* d_out, int out_size, void* d_ws, size_t ws_size,
                              hipStream_t stream) {
    (void)in_sizes; (void)n_in; (void)out_size; (void)ws_size;
    const int*   seq   = (const int*)d_in[0];
    const float* embed = (const float*)d_in[1];
    const float* nw    = (const float*)d_in[2];
    const float* ipw   = (const float*)d_in[3];
    const float* cw    = (const float*)d_in[4];
    const float* cb    = (const float*)d_in[5];
    const float* xpw   = (const float*)d_in[6];
    const float* dpw   = (const float*)d_in[7];
    const float* dpb   = (const float*)d_in[8];
    const float* al    = (const float*)d_in[9];
    const float* dd    = (const float*)d_in[10];
    const float* opw   = (const float*)d_in[11];
    const float* fnw   = (const float*)d_in[12];
    float* out = (float*)d_out;

    float* ws   = (float*)d_ws;
    float* h    = ws;                       // BT*H
    float* xn   = h    + (size_t)BT_ * H_;  // BT*H
    float* proj = xn   + (size_t)BT_ * H_;  // BT*2D
    float* xc   = proj + (size_t)BT_ * 2 * D_; // BT*D
    float* p2   = xc   + (size_t)BT_ * D_;  // BT*P2
    float* dt   = p2   + (size_t)BT_ * P2_; // BT*D
    float* y    = dt   + (size_t)BT_ * D_;  // BT*D

    embed_gather_k<<<BT_, 256, 0, stream>>>(seq, embed, h);

    for (int l = 0; l < L_; ++l) {
        rmsnorm_k<<<BT_, 256, 0, stream>>>(h, nw + (size_t)l * H_, xn);
        // in_proj: [BT,768] @ [3072,768]^T -> [BT,3072]
        gemm64_k<0><<<dim3(2 * D_ / 64, BT_ / 64), 256, 0, stream>>>(
            xn, ipw + (size_t)l * 2 * D_ * H_, proj, BT_, 2 * D_, H_);
        conv_silu_k<<<(BT_ * D_) / 256, 256, 0, stream>>>(
            proj, cw + (size_t)l * D_ * K_, cb + (size_t)l * D_, xc);
        // x_proj: [BT,1536] @ [80,1536]^T -> [BT,80]
        gemm64_k<0><<<dim3((P2_ + 63) / 64, BT_ / 64), 256, 0, stream>>>(
            xc, xpw + (size_t)l * P2_ * D_, p2, BT_, P2_, D_);
        dt_k<<<dim3(D_ / 256, BT_), 256, 0, stream>>>(
            p2, dpw + (size_t)l * D_ * R_, dpb + (size_t)l * D_, dt);
        scan_k<<<dim3(D_ / 16, B_), 256, 0, stream>>>(
            dt, xc, p2, al + (size_t)l * D_ * N_, dd + (size_t)l * D_, proj, y);
        // out_proj + residual: h += y @ [768,1536]^T
        gemm64_k<1><<<dim3(H_ / 64, BT_ / 64), 256, 0, stream>>>(
            y, opw + (size_t)l * H_ * D_, h, BT_, H_, D_);
    }

    rmsnorm_k<<<BT_, 256, 0, stream>>>(h, fnw, xn);
    // logits: [BT,768] @ [V,768]^T -> [BT,V]
    gemm128_k<0><<<dim3((V_ + 127) / 128, BT_ / 128), 256, 0, stream>>>(
        xn, embed, out, BT_, V_, H_);
}

// Round 2
// 3163.675 us; speedup vs baseline: 1.5251x; 1.5251x over previous
//
#include <hip/hip_runtime.h>
#include <cstdint>
#include <cmath>

// Mamba forward. Round 2: logits GEMM -> bf16 MFMA (m97 structure).
#define V_  50257
#define H_  768
#define D_  1536
#define N_  16
#define K_  4
#define R_  48
#define L_  2
#define B_  2
#define T_  1024
#define BT_ (B_*T_)
#define P2_ (R_ + 2*N_)   // 80
#define EPS_ 1e-5f
#define VPAD_ 50304       // 393*128, padded vocab rows for the MFMA tile

typedef short s16x8 __attribute__((ext_vector_type(8)));
typedef float f32x4 __attribute__((ext_vector_type(4)));

static __device__ __forceinline__ unsigned short f2bf(float f) {
    unsigned int u = __float_as_uint(f);
    unsigned int r = (u + 0x7FFFu + ((u >> 16) & 1u)) >> 16;
    return (unsigned short)r;
}

// ---------------------------------------------------------------------------
// Embedding gather: h[row, :] = embed[seq[row], :]
__global__ __launch_bounds__(256) void embed_gather_k(const int* __restrict__ seq,
                                                      const float* __restrict__ embed,
                                                      float* __restrict__ h) {
    int row = blockIdx.x;
    int v = seq[row];
    const float4* src = (const float4*)(embed + (size_t)v * H_);
    float4* dst = (float4*)(h + (size_t)row * H_);
    for (int c = threadIdx.x; c < H_ / 4; c += blockDim.x) dst[c] = src[c];
}

// ---------------------------------------------------------------------------
// fp32 embed [V,768] -> bf16 [VPAD_,768], zero-padded rows.
__global__ __launch_bounds__(256) void convert_embed_k(const float* __restrict__ e,
                                                       unsigned short* __restrict__ o) {
    size_t gid = (size_t)blockIdx.x * 256 + threadIdx.x;
    size_t base = gid * 8;                    // 8 elems per thread; 768 % 8 == 0
    int row = (int)(base / H_);
    uint4 out = make_uint4(0u, 0u, 0u, 0u);
    if (row < V_) {
        const float4* s = (const float4*)(e + base);
        float4 a = s[0], b = s[1];
        out.x = (unsigned)f2bf(a.x) | ((unsigned)f2bf(a.y) << 16);
        out.y = (unsigned)f2bf(a.z) | ((unsigned)f2bf(a.w) << 16);
        out.z = (unsigned)f2bf(b.x) | ((unsigned)f2bf(b.y) << 16);
        out.w = (unsigned)f2bf(b.z) | ((unsigned)f2bf(b.w) << 16);
    }
    *(uint4*)(o + base) = out;
}

// ---------------------------------------------------------------------------
// RMSNorm fp32 out
__global__ __launch_bounds__(256) void rmsnorm_k(const float* __restrict__ in,
                                                 const float* __restrict__ w,
                                                 float* __restrict__ out) {
    int row = blockIdx.x;
    const float* p = in + (size_t)row * H_;
    float vals[3];
    float ss = 0.f;
#pragma unroll
    for (int i = 0; i < 3; ++i) {
        float v = p[threadIdx.x + i * 256];
        vals[i] = v;
        ss += v * v;
    }
#pragma unroll
    for (int m = 32; m >= 1; m >>= 1) ss += __shfl_xor(ss, m);
    __shared__ float wss[4];
    if ((threadIdx.x & 63) == 0) wss[threadIdx.x >> 6] = ss;
    __syncthreads();
    float tot = wss[0] + wss[1] + wss[2] + wss[3];
    float scale = rsqrtf(tot * (1.f / H_) + EPS_);
#pragma unroll
    for (int i = 0; i < 3; ++i) {
        int c = threadIdx.x + i * 256;
        out[(size_t)row * H_ + c] = vals[i] * scale * w[c];
    }
}

// RMSNorm bf16 out (for the logits GEMM input)
__global__ __launch_bounds__(256) void rmsnorm_bf16_k(const float* __restrict__ in,
                                                      const float* __restrict__ w,
                                                      unsigned short* __restrict__ out) {
    int row = blockIdx.x;
    const float* p = in + (size_t)row * H_;
    float vals[3];
    float ss = 0.f;
#pragma unroll
    for (int i = 0; i < 3; ++i) {
        float v = p[threadIdx.x + i * 256];
        vals[i] = v;
        ss += v * v;
    }
#pragma unroll
    for (int m = 32; m >= 1; m >>= 1) ss += __shfl_xor(ss, m);
    __shared__ float wss[4];
    if ((threadIdx.x & 63) == 0) wss[threadIdx.x >> 6] = ss;
    __syncthreads();
    float tot = wss[0] + wss[1] + wss[2] + wss[3];
    float scale = rsqrtf(tot * (1.f / H_) + EPS_);
#pragma unroll
    for (int i = 0; i < 3; ++i) {
        int c = threadIdx.x + i * 256;
        out[(size_t)row * H_ + c] = f2bf(vals[i] * scale * w[c]);
    }
}

// ---------------------------------------------------------------------------
// Generic fp32 GEMM:  C[M,N] (+)= X[M,K] @ W[N,K]^T. 64x64 tile, BK=16.
template <int ADD>
__global__ __launch_bounds__(256) void gemm64_k(const float* __restrict__ X,
                                                const float* __restrict__ W,
                                                float* __restrict__ C,
                                                int M, int N, int K) {
    __shared__ __align__(16) float Xs[16][68];
    __shared__ __align__(16) float Ws[16][68];
    const int bm = blockIdx.y * 64;
    const int bn = blockIdx.x * 64;
    const int tid = threadIdx.x;
    const int tx = tid & 15;
    const int ty = tid >> 4;
    const int lr = tid >> 2;
    const int lk = (tid & 3) * 4;

    float acc[4][4];
#pragma unroll
    for (int i = 0; i < 4; ++i)
#pragma unroll
        for (int j = 0; j < 4; ++j) acc[i][j] = 0.f;

    for (int k0 = 0; k0 < K; k0 += 16) {
        float4 xv = make_float4(0.f, 0.f, 0.f, 0.f);
        float4 wv = make_float4(0.f, 0.f, 0.f, 0.f);
        int xr = bm + lr;
        if (xr < M) xv = *(const float4*)(X + (size_t)xr * K + k0 + lk);
        int wr = bn + lr;
        if (wr < N) wv = *(const float4*)(W + (size_t)wr * K + k0 + lk);
        Xs[lk + 0][lr] = xv.x; Xs[lk + 1][lr] = xv.y; Xs[lk + 2][lr] = xv.z; Xs[lk + 3][lr] = xv.w;
        Ws[lk + 0][lr] = wv.x; Ws[lk + 1][lr] = wv.y; Ws[lk + 2][lr] = wv.z; Ws[lk + 3][lr] = wv.w;
        __syncthreads();
#pragma unroll
        for (int kk = 0; kk < 16; ++kk) {
            float4 av = *(const float4*)&Xs[kk][ty * 4];
            float4 bv = *(const float4*)&Ws[kk][tx * 4];
            float a[4] = {av.x, av.y, av.z, av.w};
            float b[4] = {bv.x, bv.y, bv.z, bv.w};
#pragma unroll
            for (int i = 0; i < 4; ++i)
#pragma unroll
                for (int j = 0; j < 4; ++j) acc[i][j] = fmaf(a[i], b[j], acc[i][j]);
        }
        __syncthreads();
    }
#pragma unroll
    for (int i = 0; i < 4; ++i) {
        int row = bm + ty * 4 + i;
        if (row >= M) continue;
        int col = bn + tx * 4;
        size_t idx = (size_t)row * N + col;
        if (col + 3 < N) {
            float4* cp = (float4*)(C + idx);
            float4 v = make_float4(acc[i][0], acc[i][1], acc[i][2], acc[i][3]);
            if (ADD) {
                float4 o = *cp;
                v.x += o.x; v.y += o.y; v.z += o.z; v.w += o.w;
            }
            *cp = v;
        } else {
#pragma unroll
            for (int j = 0; j < 4; ++j) {
                if (col + j < N) {
                    if (ADD) C[idx + j] += acc[i][j];
                    else C[idx + j] = acc[i][j];
                }
            }
        }
    }
}

// ---------------------------------------------------------------------------
// Logits GEMM, bf16 MFMA, m97 structure: 128x128 tile, BK=32, 4 waves (2x2),
// global_load_lds width=16, single LDS buffer, 2-barrier K-loop.
// C[2048, V] = Xb[2048,768] @ Eb[VPAD_,768]^T  (both bf16 K-major, fp32 out)
__global__ __launch_bounds__(256) void gemm_logits_bf16_k(const unsigned short* __restrict__ Xb,
                                                          const unsigned short* __restrict__ Eb,
                                                          float* __restrict__ C) {
    __shared__ unsigned short As[128 * 32];
    __shared__ unsigned short Bs[128 * 32];
    const int tid = threadIdx.x;
    const int lane = tid & 63;
    const int wid = tid >> 6;
    const int wm = wid >> 1, wn = wid & 1;
    const int bm = blockIdx.y * 128;
    const int bn = blockIdx.x * 128;

    const int sr = tid >> 2;          // staging row 0..63
    const int sc = (tid & 3) * 8;     // staging col (bf16 elems)
    const unsigned short* gA = Xb + (size_t)(bm + sr) * H_ + sc;
    const unsigned short* gB = Eb + (size_t)(bn + sr) * H_ + sc;

    f32x4 acc[4][4] = {};
    const int fr = lane & 15;         // fragment row (A) / col (B)
    const int fk = (lane >> 4) * 8;   // fragment k offset

    for (int k0 = 0; k0 < H_; k0 += 32) {
        __builtin_amdgcn_global_load_lds(
            (const __attribute__((address_space(1))) void*)(gA + k0),
            (__attribute__((address_space(3))) void*)&As[sr * 32 + sc], 16, 0, 0);
        __builtin_amdgcn_global_load_lds(
            (const __attribute__((address_space(1))) void*)(gA + k0 + 64 * H_),
            (__attribute__((address_space(3))) void*)&As[(64 + sr) * 32 + sc], 16, 0, 0);
        __builtin_amdgcn_global_load_lds(
            (const __attribute__((address_space(1))) void*)(gB + k0),
            (__attribute__((address_space(3))) void*)&Bs[sr * 32 + sc], 16, 0, 0);
        __builtin_amdgcn_global_load_lds(
            (const __attribute__((address_space(1))) void*)(gB + k0 + 64 * H_),
            (__attribute__((address_space(3))) void*)&Bs[(64 + sr) * 32 + sc], 16, 0, 0);
        __syncthreads();
        s16x8 a[4], b[4];
#pragma unroll
        for (int i = 0; i < 4; ++i) {
            a[i] = *(const s16x8*)&As[(wm * 64 + i * 16 + fr) * 32 + fk];
            b[i] = *(const s16x8*)&Bs[(wn * 64 + i * 16 + fr) * 32 + fk];
        }
#pragma unroll
        for (int i = 0; i < 4; ++i)
#pragma unroll
            for (int j = 0; j < 4; ++j)
                acc[i][j] = __builtin_amdgcn_mfma_f32_16x16x32_bf16(a[i], b[j], acc[i][j], 0, 0, 0);
        __syncthreads();
    }

    const int orow = (lane >> 4) * 4;
#pragma unroll
    for (int i = 0; i < 4; ++i) {
        int row = bm + wm * 64 + i * 16 + orow;
#pragma unroll
        for (int j = 0; j < 4; ++j) {
            int col = bn + wn * 64 + j * 16 + fr;
            if (col < V_) {
#pragma unroll
                for (int q = 0; q < 4; ++q)
                    C[(size_t)(row + q) * V_ + col] = acc[i][j][q];
            }
        }
    }
}

// ---------------------------------------------------------------------------
// Causal depthwise conv (K=4) + SiLU.
__global__ __launch_bounds__(256) void conv_silu_k(const float* __restrict__ proj,
                                                   const float* __restrict__ cw,
                                                   const float* __restrict__ cb,
                                                   float* __restrict__ xc) {
    int idx = blockIdx.x * 256 + threadIdx.x;   // over BT*D
    int d = idx % D_;
    int row = idx / D_;
    int t = row & (T_ - 1);
    float acc = cb[d];
    const float* base = proj + (size_t)row * (2 * D_) + d;
#pragma unroll
    for (int k = 0; k < K_; ++k) {
        int tt = t - (K_ - 1) + k;
        if (tt >= 0) acc = fmaf(base[(ptrdiff_t)(k - (K_ - 1)) * (2 * D_)], cw[d * K_ + k], acc);
    }
    xc[idx] = acc / (1.f + expf(-acc));  // silu
}

// ---------------------------------------------------------------------------
// dt = softplus(dt_in @ dpw^T + dpb)
__global__ __launch_bounds__(256) void dt_k(const float* __restrict__ p2,
                                            const float* __restrict__ dpw,
                                            const float* __restrict__ dpb,
                                            float* __restrict__ dt) {
    int row = blockIdx.y;
    int d = blockIdx.x * 256 + threadIdx.x;
    __shared__ float din[R_];
    if (threadIdx.x < R_) din[threadIdx.x] = p2[(size_t)row * P2_ + threadIdx.x];
    __syncthreads();
    float acc = dpb[d];
    const float* wrow = dpw + (size_t)d * R_;
#pragma unroll
    for (int r = 0; r < R_; ++r) acc = fmaf(din[r], wrow[r], acc);
    float sp = (acc > 20.f) ? acc : log1pf(expf(acc));
    dt[(size_t)row * D_ + d] = sp;
}

// ---------------------------------------------------------------------------
// Selective scan along T, fused with C-contraction, D-skip, gate*silu.
__global__ __launch_bounds__(256) void scan_k(const float* __restrict__ dt,
                                              const float* __restrict__ xc,
                                              const float* __restrict__ p2,
                                              const float* __restrict__ al,
                                              const float* __restrict__ Dp,
                                              const float* __restrict__ proj,
                                              float* __restrict__ y) {
    int b = blockIdx.y;
    int n = threadIdx.x & 15;
    int dl = threadIdx.x >> 4;
    int d = blockIdx.x * 16 + dl;
    float A = -expf(al[(size_t)d * N_ + n]);
    float dd = Dp[d];
    float h = 0.f;
    const size_t rowbase = (size_t)b * T_;
    for (int t = 0; t < T_; ++t) {
        size_t row = rowbase + t;
        float dtv = dt[row * D_ + d];
        float xcv = xc[row * D_ + d];
        float Bv = p2[row * P2_ + R_ + n];
        float Cv = p2[row * P2_ + R_ + N_ + n];
        float dA = expf(dtv * A);
        h = fmaf(dA, h, (dtv * xcv) * Bv);
        float contrib = h * Cv;
        contrib += __shfl_xor(contrib, 1);
        contrib += __shfl_xor(contrib, 2);
        contrib += __shfl_xor(contrib, 4);
        contrib += __shfl_xor(contrib, 8);
        if (n == 0) {
            float yv = contrib + xcv * dd;
            float g = proj[row * (2 * D_) + D_ + d];
            yv *= g / (1.f + expf(-g));
            y[row * D_ + d] = yv;
        }
    }
}

// ---------------------------------------------------------------------------
extern "C" void kernel_launch(void* const* d_in, const int* in_sizes, int n_in,
                              void* d_out, int out_size, void* d_ws, size_t ws_size,
                              hipStream_t stream) {
    (void)in_sizes; (void)n_in; (void)out_size; (void)ws_size;
    const int*   seq   = (const int*)d_in[0];
    const float* embed = (const float*)d_in[1];
    const float* nw    = (const float*)d_in[2];
    const float* ipw   = (const float*)d_in[3];
    const float* cw    = (const float*)d_in[4];
    const float* cb    = (const float*)d_in[5];
    const float* xpw   = (const float*)d_in[6];
    const float* dpw   = (const float*)d_in[7];
    const float* dpb   = (const float*)d_in[8];
    const float* al    = (const float*)d_in[9];
    const float* dd    = (const float*)d_in[10];
    const float* opw   = (const float*)d_in[11];
    const float* fnw   = (const float*)d_in[12];
    float* out = (float*)d_out;

    float* ws   = (float*)d_ws;
    float* h    = ws;                          // BT*H
    float* xn   = h    + (size_t)BT_ * H_;     // BT*H
    float* proj = xn   + (size_t)BT_ * H_;     // BT*2D
    float* xc   = proj + (size_t)BT_ * 2 * D_; // BT*D
    float* p2   = xc   + (size_t)BT_ * D_;     // BT*P2
    float* dt   = p2   + (size_t)BT_ * P2_;    // BT*D
    float* y    = dt   + (size_t)BT_ * D_;     // BT*D
    unsigned short* xnb = (unsigned short*)(y + (size_t)BT_ * D_);  // BT*H bf16
    unsigned short* ebf = xnb + (size_t)BT_ * H_;                   // VPAD_*H bf16

    // One-time (per launch) bf16 conversion of tied embedding, padded to VPAD_.
    convert_embed_k<<<(VPAD_ * H_) / (256 * 8), 256, 0, stream>>>(embed, ebf);

    embed_gather_k<<<BT_, 256, 0, stream>>>(seq, embed, h);

    for (int l = 0; l < L_; ++l) {
        rmsnorm_k<<<BT_, 256, 0, stream>>>(h, nw + (size_t)l * H_, xn);
        gemm64_k<0><<<dim3(2 * D_ / 64, BT_ / 64), 256, 0, stream>>>(
            xn, ipw + (size_t)l * 2 * D_ * H_, proj, BT_, 2 * D_, H_);
        conv_silu_k<<<(BT_ * D_) / 256, 256, 0, stream>>>(
            proj, cw + (size_t)l * D_ * K_, cb + (size_t)l * D_, xc);
        gemm64_k<0><<<dim3((P2_ + 63) / 64, BT_ / 64), 256, 0, stream>>>(
            xc, xpw + (size_t)l * P2_ * D_, p2, BT_, P2_, D_);
        dt_k<<<dim3(D_ / 256, BT_), 256, 0, stream>>>(
            p2, dpw + (size_t)l * D_ * R_, dpb + (size_t)l * D_, dt);
        scan_k<<<dim3(D_ / 16, B_), 256, 0, stream>>>(
            dt, xc, p2, al + (size_t)l * D_ * N_, dd + (size_t)l * D_, proj, y);
        gemm64_k<1><<<dim3(H_ / 64, BT_ / 64), 256, 0, stream>>>(
            y, opw + (size_t)l * H_ * D_, h, BT_, H_, D_);
    }

    rmsnorm_bf16_k<<<BT_, 256, 0, stream>>>(h, fnw, xnb);
    // logits: [2048,768]bf16 @ [VPAD_,768]bf16^T -> [2048,V] fp32
    gemm_logits_bf16_k<<<dim3(VPAD_ / 128, BT_ / 128), 256, 0, stream>>>(xnb, ebf, out);
}